// Round 1
// baseline (3658.237 us; speedup 1.0000x reference)
//
#include <hip/hip_runtime.h>
#include <hip/hip_bf16.h>

#define B_ 256
#define T_ 20
#define H_ 512
#define WV_ 301
#define F_ 196
#define C_ 512
#define V_ 9871

#define KC 16

typedef __attribute__((ext_vector_type(8))) short short8;
typedef __attribute__((ext_vector_type(4))) float f32x4;
typedef unsigned short ushort_t;

__device__ __forceinline__ float sigm(float x) { return 1.f / (1.f + expf(-x)); }

__device__ __forceinline__ void gload_lds16(const void* g, void* l) {
  __builtin_amdgcn_global_load_lds(
      (const __attribute__((address_space(1))) unsigned int*)g,
      (__attribute__((address_space(3))) unsigned int*)l, 16, 0, 0);
}

// ---------------------------------------------------------------------------
// init: x_seq [T*B][304] (teacher-forced, shifted, zero-padded cols 301..303),
//       Acat [B][816] = [inp(0..300) | pad | h(304..815)] zeroed, cstate zeroed
// ---------------------------------------------------------------------------
__global__ __launch_bounds__(256) void k_init(float* __restrict__ x_seq,
                                              float* __restrict__ Acat,
                                              float* __restrict__ cst,
                                              const float* __restrict__ wvecs) {
  int idx = blockIdx.x * 256 + threadIdx.x;
  const int XS = T_ * B_ * 304;
  const int AC = B_ * 816;
  const int CS = B_ * H_;
  if (idx < XS) {
    int r = idx / 304, k = idx - r * 304;
    int t = r >> 8, b = r & 255;
    float v = 0.f;
    if (k < WV_ && t > 0) v = wvecs[((size_t)b * T_ + (t - 1)) * WV_ + k];
    x_seq[idx] = v;
  } else if (idx < XS + AC) {
    Acat[idx - XS] = 0.f;
  } else if (idx < XS + AC + CS) {
    cst[idx - XS - AC] = 0.f;
  }
}

// ---------------------------------------------------------------------------
// pack: Wh_pack [2756][512] = [attn_W h-part | gate_W | Whh (gate-interleaved)]
//       Wih_pack [2048][304] gate-interleaved (row 4*jj+g = Wih[g*512+jj]),
//       bsum [2048] = bih+bhh interleaved, Wvb [9984][512] bf16 zero-padded
// ---------------------------------------------------------------------------
__global__ __launch_bounds__(256) void k_pack(
    float* __restrict__ Whp, float* __restrict__ Wihp, float* __restrict__ bsum,
    __hip_bfloat16* __restrict__ Wvb,
    const float* __restrict__ attn_W, const float* __restrict__ gate_W,
    const float* __restrict__ Whh, const float* __restrict__ Wih,
    const float* __restrict__ bih, const float* __restrict__ bhh,
    const float* __restrict__ vW) {
  int idx = blockIdx.x * 256 + threadIdx.x;
  const int R1 = 2756 * 512;
  const int R2 = 2048 * 304;
  const int R3 = 2048;
  const int R4 = 9984 * 512;
  if (idx < R1) {
    int p = idx >> 9, k = idx & 511;
    float v;
    if (p < 196) v = attn_W[p * 813 + 301 + k];
    else if (p < 708) v = gate_W[(size_t)(p - 196) * 512 + k];
    else {
      int q = p - 708;
      int g = q & 3, jj = q >> 2;
      v = Whh[(size_t)(g * 512 + jj) * 512 + k];
    }
    Whp[idx] = v;
  } else if (idx < R1 + R2) {
    int i2 = idx - R1;
    int p = i2 / 304, k = i2 - p * 304;
    int g = p & 3, jj = p >> 2;
    Wihp[i2] = (k < 301) ? Wih[(size_t)(g * 512 + jj) * 301 + k] : 0.f;
  } else if (idx < R1 + R2 + R3) {
    int p = idx - R1 - R2;
    int g = p & 3, jj = p >> 2;
    int o = g * 512 + jj;
    bsum[p] = bih[o] + bhh[o];
  } else if (idx < R1 + R2 + R3 + R4) {
    int i2 = idx - R1 - R2 - R3;
    int n = i2 >> 9, k = i2 & 511;
    Wvb[i2] = __float2bfloat16(n < V_ ? vW[(size_t)n * 512 + k] : 0.f);
  }
}

// ---------------------------------------------------------------------------
// generic fp32 GEMM: C[M,N] = epi(A[M,Kpad] @ W[N,K].T + bias + addend)
// A must be float4-aligned with lda%4==0 (buffers padded); M = gridDim.x*64.
// EPI: 0 = plain(+bias,+addend), 1 = relu(+bias,+addend), 2 = fused LSTM cell
// (EPI 2: columns are gate-interleaved 4*jj+g; bias/addend mandatory)
// ---------------------------------------------------------------------------
template <int EPI>
__global__ __launch_bounds__(256) void sgemm_k(
    const float* __restrict__ A, int lda,
    const float* __restrict__ W, int ldw, int Kreal,
    const float* __restrict__ bias,
    const float* __restrict__ addend, int ld_add,
    float* __restrict__ C, int ldc,
    int N, int Kpad,
    float* __restrict__ cstate, __hip_bfloat16* __restrict__ hb_t) {
  __shared__ __align__(16) float As[KC][68];
  __shared__ __align__(16) float Ws[KC][68];
  const int tid = threadIdx.x;
  const int m0 = blockIdx.x * 64, n0 = blockIdx.y * 64;
  const int sr = tid >> 2, sq = tid & 3;  // staging: row 0..63, K-quarter 0..3
  const int tm = tid >> 4, tn = tid & 15;
  float acc[4][4] = {};

  for (int k0 = 0; k0 < Kpad; k0 += KC) {
    __syncthreads();
    {  // stage A (always in-bounds: buffers K-padded, M multiple of 64)
      const float4 v = *(const float4*)(A + (size_t)(m0 + sr) * lda + k0 + sq * 4);
      As[sq * 4 + 0][sr] = v.x;
      As[sq * 4 + 1][sr] = v.y;
      As[sq * 4 + 2][sr] = v.z;
      As[sq * 4 + 3][sr] = v.w;
    }
    {  // stage W (scalar: ldw may be odd; guard N and Kreal tails)
      int n = n0 + sr;
      float w0 = 0, w1 = 0, w2 = 0, w3 = 0;
      if (n < N) {
        const float* wp = W + (size_t)n * ldw + k0 + sq * 4;
        int rem = Kreal - (k0 + sq * 4);
        if (rem > 0) w0 = wp[0];
        if (rem > 1) w1 = wp[1];
        if (rem > 2) w2 = wp[2];
        if (rem > 3) w3 = wp[3];
      }
      Ws[sq * 4 + 0][sr] = w0;
      Ws[sq * 4 + 1][sr] = w1;
      Ws[sq * 4 + 2][sr] = w2;
      Ws[sq * 4 + 3][sr] = w3;
    }
    __syncthreads();
#pragma unroll
    for (int kk = 0; kk < KC; kk++) {
      float4 a = *(const float4*)&As[kk][tm * 4];
      float4 w = *(const float4*)&Ws[kk][tn * 4];
      float av[4] = {a.x, a.y, a.z, a.w};
      float wv[4] = {w.x, w.y, w.z, w.w};
#pragma unroll
      for (int i = 0; i < 4; i++)
#pragma unroll
        for (int j = 0; j < 4; j++) acc[i][j] = fmaf(av[i], wv[j], acc[i][j]);
    }
  }

  const int row0 = m0 + tm * 4, col0 = n0 + tn * 4;
  if (EPI == 2) {
    int jj = col0 >> 2;
#pragma unroll
    for (int i = 0; i < 4; i++) {
      int b = row0 + i;
      float gi = acc[i][0] + bias[col0 + 0] + addend[(size_t)b * ld_add + col0 + 0];
      float gf = acc[i][1] + bias[col0 + 1] + addend[(size_t)b * ld_add + col0 + 1];
      float gg = acc[i][2] + bias[col0 + 2] + addend[(size_t)b * ld_add + col0 + 2];
      float go = acc[i][3] + bias[col0 + 3] + addend[(size_t)b * ld_add + col0 + 3];
      float cold = cstate[b * 512 + jj];
      float cn = sigm(gf) * cold + sigm(gi) * tanhf(gg);
      float hn = sigm(go) * tanhf(cn);
      cstate[b * 512 + jj] = cn;
      C[(size_t)b * ldc + jj] = hn;  // C points at Acat h-region
      hb_t[b * 512 + jj] = __float2bfloat16(hn);
    }
  } else {
#pragma unroll
    for (int i = 0; i < 4; i++)
#pragma unroll
      for (int j = 0; j < 4; j++) {
        int col = col0 + j;
        if (col < N) {
          float v = acc[i][j];
          if (bias) v += bias[col];
          if (addend) v += addend[(size_t)(row0 + i) * ld_add + col];
          if (EPI == 1) v = fmaxf(v, 0.f);
          C[(size_t)(row0 + i) * ldc + col] = v;
        }
      }
  }
}

// ---------------------------------------------------------------------------
// per-step fused: softmax(attn_x + h@Wh) -> ctx = (aw . enc) * sigmoid(gate)
// one block per batch row
// ---------------------------------------------------------------------------
__global__ __launch_bounds__(256) void attn_einsum(
    const float* __restrict__ attn_x_t, const float* __restrict__ hproj,
    const float* __restrict__ enc, const float* __restrict__ gate_b,
    float* __restrict__ ctx) {
  int b = blockIdx.x, tid = threadIdx.x;
  __shared__ __align__(16) float aw[200];
  __shared__ float red[16];
  float sv = -1e30f;
  if (tid < F_) sv = attn_x_t[b * F_ + tid] + hproj[(size_t)b * 2756 + tid];
  float m = sv;
#pragma unroll
  for (int o = 32; o > 0; o >>= 1) m = fmaxf(m, __shfl_xor(m, o));
  if ((tid & 63) == 0) red[tid >> 6] = m;
  __syncthreads();
  float mall = fmaxf(fmaxf(red[0], red[1]), fmaxf(red[2], red[3]));
  float e = (tid < F_) ? expf(sv - mall) : 0.f;
  float s = e;
#pragma unroll
  for (int o = 32; o > 0; o >>= 1) s += __shfl_xor(s, o);
  if ((tid & 63) == 0) red[8 + (tid >> 6)] = s;
  __syncthreads();
  float sall = red[8] + red[9] + red[10] + red[11];
  if (tid < F_) aw[tid] = e / sall;
  __syncthreads();
  const float4* aw4 = (const float4*)aw;
  for (int c = tid; c < C_; c += 256) {
    const float4* e4 = (const float4*)(enc + ((size_t)b * C_ + c) * F_);
    float acc = 0.f;
#pragma unroll
    for (int f = 0; f < F_ / 4; f++) {
      float4 ev = e4[f];
      float4 av = aw4[f];
      acc = fmaf(ev.x, av.x, fmaf(ev.y, av.y, fmaf(ev.z, av.z, fmaf(ev.w, av.w, acc))));
    }
    float g = sigm(hproj[(size_t)b * 2756 + 196 + c] + gate_b[c]);
    ctx[b * C_ + c] = acc * g;
  }
}

// ---------------------------------------------------------------------------
// vocab head: out[b][t][v] = hb[t*B+b] . Wvb[v] + vbias[v]
// bf16 MFMA 16x16x32, 128x128 tile, BK=32, 4 waves, global_load_lds staging
// ---------------------------------------------------------------------------
__global__ __launch_bounds__(256) void vocab_gemm(
    const ushort_t* __restrict__ Ab,   // hb [5120][512] bf16
    const ushort_t* __restrict__ Wb,   // [9984][512] bf16 (zero-padded)
    const float* __restrict__ vbias,   // [9871]
    float* __restrict__ out) {
  __shared__ ushort_t As[128 * 32];
  __shared__ ushort_t Bs[128 * 32];
  const int tid = threadIdx.x;
  const int lane = tid & 63, wid = tid >> 6;
  const int m0 = blockIdx.x * 128, n0 = blockIdx.y * 128;
  const int srow = tid >> 2, sq = tid & 3;
  const int K = 512;
  f32x4 acc[4][4] = {};

  for (int k0 = 0; k0 < K; k0 += 32) {
    __syncthreads();
#pragma unroll
    for (int c2 = 0; c2 < 2; c2++) {
      const ushort_t* ga = Ab + (size_t)(m0 + c2 * 64 + srow) * K + k0 + sq * 8;
      gload_lds16(ga, As + c2 * 2048 + wid * 512);
      const ushort_t* gb = Wb + (size_t)(n0 + c2 * 64 + srow) * K + k0 + sq * 8;
      gload_lds16(gb, Bs + c2 * 2048 + wid * 512);
    }
    __syncthreads();
    const int wr = (wid >> 1) * 64, wc = (wid & 1) * 64;
    const int fr = lane & 15, fk = (lane >> 4) * 8;
    short8 a[4], b[4];
#pragma unroll
    for (int mi = 0; mi < 4; mi++)
      a[mi] = *(const short8*)&As[(wr + mi * 16 + fr) * 32 + fk];
#pragma unroll
    for (int ni = 0; ni < 4; ni++)
      b[ni] = *(const short8*)&Bs[(wc + ni * 16 + fr) * 32 + fk];
#pragma unroll
    for (int mi = 0; mi < 4; mi++)
#pragma unroll
      for (int ni = 0; ni < 4; ni++)
        acc[mi][ni] = __builtin_amdgcn_mfma_f32_16x16x32_bf16(a[mi], b[ni], acc[mi][ni], 0, 0, 0);
  }

  const int wr = (wid >> 1) * 64, wc = (wid & 1) * 64;
  const int cr = (lane >> 4) * 4, cc = lane & 15;
#pragma unroll
  for (int ni = 0; ni < 4; ni++) {
    int col = n0 + wc + ni * 16 + cc;
    if (col < V_) {
      float bv = vbias[col];
#pragma unroll
      for (int mi = 0; mi < 4; mi++) {
#pragma unroll
        for (int v = 0; v < 4; v++) {
          int r = m0 + wr + mi * 16 + cr + v;
          int t = r >> 8, bb = r & 255;
          out[((size_t)bb * T_ + t) * V_ + col] = acc[mi][ni][v] + bv;
        }
      }
    }
  }
}

// ---------------------------------------------------------------------------
extern "C" void kernel_launch(void* const* d_in, const int* in_sizes, int n_in,
                              void* d_out, int out_size, void* d_ws, size_t ws_size,
                              hipStream_t stream) {
  const float* enc   = (const float*)d_in[0];
  const float* wvec  = (const float*)d_in[1];
  const float* attnW = (const float*)d_in[2];
  const float* attnb = (const float*)d_in[3];
  const float* combW = (const float*)d_in[4];
  const float* combb = (const float*)d_in[5];
  const float* gateW = (const float*)d_in[6];
  const float* gateb = (const float*)d_in[7];
  const float* Wih   = (const float*)d_in[8];
  const float* Whh   = (const float*)d_in[9];
  const float* bih   = (const float*)d_in[10];
  const float* bhh   = (const float*)d_in[11];
  const float* vW    = (const float*)d_in[12];
  const float* vb    = (const float*)d_in[13];
  float* out = (float*)d_out;

  char* ws = (char*)d_ws;
  size_t off = 0;
  auto alloc = [&](size_t bytes) {
    void* p = ws + off;
    off += (bytes + 255) & ~(size_t)255;
    return p;
  };
  float* x_seq  = (float*)alloc((size_t)T_ * B_ * 304 * 4);
  float* attn_x = (float*)alloc((size_t)T_ * B_ * F_ * 4);
  float* comb_x = (float*)alloc((size_t)T_ * B_ * WV_ * 4);
  float* Whp    = (float*)alloc((size_t)2756 * 512 * 4);
  float* Wihp   = (float*)alloc((size_t)2048 * 304 * 4);
  float* bsum   = (float*)alloc((size_t)2048 * 4);
  float* Acat   = (float*)alloc((size_t)B_ * 816 * 4);
  float* cst    = (float*)alloc((size_t)B_ * 512 * 4);
  float* hproj  = (float*)alloc((size_t)B_ * 2756 * 4);
  float* ctx    = (float*)alloc((size_t)B_ * 512 * 4);
  __hip_bfloat16* hb  = (__hip_bfloat16*)alloc((size_t)T_ * B_ * 512 * 2);
  __hip_bfloat16* Wvb = (__hip_bfloat16*)alloc((size_t)9984 * 512 * 2);

  {
    int tot = T_ * B_ * 304 + B_ * 816 + B_ * 512;
    k_init<<<(tot + 255) / 256, 256, 0, stream>>>(x_seq, Acat, cst, wvec);
  }
  {
    int tot = 2756 * 512 + 2048 * 304 + 2048 + 9984 * 512;
    k_pack<<<(tot + 255) / 256, 256, 0, stream>>>(Whp, Wihp, bsum, Wvb, attnW,
                                                  gateW, Whh, Wih, bih, bhh, vW);
  }
  // precompute x-projections for all (t,b)
  sgemm_k<0><<<dim3(80, 4), 256, 0, stream>>>(x_seq, 304, attnW, 813, 301, attnb,
                                              nullptr, 0, attn_x, 196, 196, 304,
                                              nullptr, nullptr);
  sgemm_k<0><<<dim3(80, 5), 256, 0, stream>>>(x_seq, 304, combW, 813, 301, combb,
                                              nullptr, 0, comb_x, 301, 301, 304,
                                              nullptr, nullptr);
  for (int t = 0; t < T_; t++) {
    // hproj = h @ [attn_Wh | gate_W | Whh(interleaved)].T   [256, 2756]
    sgemm_k<0><<<dim3(4, 44), 256, 0, stream>>>(Acat + 304, 816, Whp, 512, 512,
                                                nullptr, nullptr, 0, hproj, 2756,
                                                2756, 512, nullptr, nullptr);
    // softmax + context einsum + gate
    attn_einsum<<<256, 256, 0, stream>>>(attn_x + (size_t)t * B_ * F_, hproj, enc,
                                         gateb, ctx);
    // inp = relu(comb_x + ctx @ comb_Wc.T) -> Acat[:,0:301]
    sgemm_k<1><<<dim3(4, 5), 256, 0, stream>>>(ctx, 512, combW + 301, 813, 512,
                                               nullptr, comb_x + (size_t)t * B_ * WV_,
                                               WV_, Acat, 816, 301, 512, nullptr,
                                               nullptr);
    // gates = inp @ Wih.T + (h@Whh.T from hproj) + biases; fused LSTM cell
    sgemm_k<2><<<dim3(4, 32), 256, 0, stream>>>(Acat, 816, Wihp, 304, 304, bsum,
                                                hproj + 708, 2756, Acat + 304, 816,
                                                2048, 304, cst,
                                                hb + (size_t)t * B_ * 512);
  }
  vocab_gemm<<<dim3(40, 78), 256, 0, stream>>>((const ushort_t*)hb,
                                               (const ushort_t*)Wvb, vb, out);
}